// Round 2
// baseline (490.631 us; speedup 1.0000x reference)
//
#include <hip/hip_runtime.h>

// ---------------- Problem constants ----------------
#define BATCH 16
#define TSEQ  4096
#define HDIM  512
#define NDIM  512
#define NCHUNK 64
#define LCHUNK 64   // TSEQ / NCHUNK

using f32x4  = __attribute__((ext_vector_type(4))) float;
using bf16x8 = __attribute__((ext_vector_type(8))) short;

typedef const __attribute__((address_space(1))) void GV;
typedef __attribute__((address_space(3))) void LV;

__device__ __forceinline__ void gload16(const void* g, void* l) {
  __builtin_amdgcn_global_load_lds((GV*)g, (LV*)l, 16, 0, 0);
}

__device__ __forceinline__ unsigned short f2bf(float f) {
  unsigned u = __float_as_uint(f);
  unsigned r = (u + 0x7fffu + ((u >> 16) & 1u)) >> 16;
  return (unsigned short)r;
}

// ---------------- Param prep ----------------
__global__ void prep_params(const float* __restrict__ nu_log,
                            const float* __restrict__ theta_log,
                            float* lam_re, float* lam_im, float* gam,
                            float* lamL_re, float* lamL_im) {
  int n = threadIdx.x;  // 512 threads, 1 block
  float en = expf(nu_log[n]);
  float th = expf(theta_log[n]);
  float r  = expf(-en);
  lam_re[n] = r * cosf(th);
  lam_im[n] = r * sinf(th);
  float r2 = expf(-2.f * en);
  gam[n] = sqrtf(fmaxf(1.f - r2, 0.f));
  float rL  = expf(-(float)LCHUNK * en);
  float thL = (float)LCHUNK * th;
  lamL_re[n] = rL * cosf(thL);
  lamL_im[n] = rL * sinf(thL);
}

// Bcat[2n][h] = bf16(gamma[n]*B_re[n][h]); Bcat[2n+1][h] = bf16(gamma[n]*B_im[n][h])
__global__ void prep_bcat(const float* __restrict__ B_re, const float* __restrict__ B_im,
                          const float* __restrict__ gam, unsigned short* __restrict__ Bcat) {
  int idx = blockIdx.x * 256 + threadIdx.x;  // 1024*512 total
  int h   = idx & (HDIM - 1);
  int row = idx >> 9;
  int n   = row >> 1;
  float g = gam[n];
  float v = (row & 1) ? B_im[n * HDIM + h] : B_re[n * HDIM + h];
  Bcat[idx] = f2bf(g * v);
}

// Ccat[h][2n] = bf16(C_re[h][n]); Ccat[h][2n+1] = bf16(-C_im[h][n])
__global__ void prep_ccat(const float* __restrict__ C_re, const float* __restrict__ C_im,
                          unsigned short* __restrict__ Ccat) {
  int idx = blockIdx.x * 256 + threadIdx.x;  // 512*1024 total
  int col = idx & (2 * NDIM - 1);
  int h   = idx >> 10;
  int n   = col >> 1;
  float v = (col & 1) ? -C_im[h * NDIM + n] : C_re[h * NDIM + n];
  Ccat[idx] = f2bf(v);
}

// f32 -> bf16 conversion of u, vectorized x4
__global__ void conv_u(const float4* __restrict__ u, ushort4* __restrict__ ub, int n4) {
  int idx = blockIdx.x * 256 + threadIdx.x;
  if (idx >= n4) return;
  float4 v = u[idx];
  ushort4 o;
  o.x = f2bf(v.x); o.y = f2bf(v.y); o.z = f2bf(v.z); o.w = f2bf(v.w);
  ub[idx] = o;
}

// ---------------- bf16 MFMA GEMM: Co[M,Nd] = A[M,K] @ Bm[Nd,K]^T (+ epilogue) ----------------
template <bool EPI>
__global__ __launch_bounds__(256)
void gemm_bt(const unsigned short* __restrict__ A, const unsigned short* __restrict__ Bm,
             float* __restrict__ Co, int K, int Nd,
             const float* __restrict__ u, const float* __restrict__ Dv) {
  __shared__ unsigned short lds_a[128 * 64];
  __shared__ unsigned short lds_b[128 * 64];
  int tid  = threadIdx.x;
  int wave = tid >> 6, lane = tid & 63;
  int wr = (wave >> 1) * 64, wc = (wave & 1) * 64;
  long row0 = (long)blockIdx.x * 128;
  long col0 = (long)blockIdx.y * 128;

  f32x4 acc[4][4];
#pragma unroll
  for (int i = 0; i < 4; i++)
#pragma unroll
    for (int j = 0; j < 4; j++) acc[i][j] = (f32x4){0.f, 0.f, 0.f, 0.f};

  int lrow = lane >> 3;        // 0..7   row within 8-row chunk
  int lk   = (lane & 7) * 8;   // bf16 offset within 64-wide K tile

  for (int kt = 0; kt < K; kt += 64) {
    __syncthreads();  // previous iter's LDS reads complete before restage
#pragma unroll
    for (int l = 0; l < 4; l++) {
      int q = l * 4 + wave;  // 0..15 chunk of 8 rows
      gload16(A  + (row0 + q * 8 + lrow) * (long)K + kt + lk, &lds_a[q * 512]);
      gload16(Bm + (col0 + q * 8 + lrow) * (long)K + kt + lk, &lds_b[q * 512]);
    }
    __syncthreads();  // compiler drains vmcnt(0) before barrier
#pragma unroll
    for (int kk = 0; kk < 64; kk += 32) {
      bf16x8 af[4], bf[4];
      int rsub = lane & 15;
      int ksub = kk + ((lane >> 4) << 3);
#pragma unroll
      for (int i = 0; i < 4; i++)
        af[i] = *(const bf16x8*)&lds_a[(wr + i * 16 + rsub) * 64 + ksub];
#pragma unroll
      for (int j = 0; j < 4; j++)
        bf[j] = *(const bf16x8*)&lds_b[(wc + j * 16 + rsub) * 64 + ksub];
#pragma unroll
      for (int i = 0; i < 4; i++)
#pragma unroll
        for (int j = 0; j < 4; j++)
          acc[i][j] = __builtin_amdgcn_mfma_f32_16x16x32_bf16(af[i], bf[j], acc[i][j], 0, 0, 0);
    }
  }

  int r4 = (lane >> 4) * 4;
  int cc = lane & 15;
#pragma unroll
  for (int i = 0; i < 4; i++) {
#pragma unroll
    for (int j = 0; j < 4; j++) {
      long col = col0 + wc + j * 16 + cc;
#pragma unroll
      for (int r = 0; r < 4; r++) {
        long row = row0 + wr + i * 16 + r4 + r;
        float v = acc[i][j][r];
        if (EPI) v += Dv[col] * u[row * (long)Nd + col];
        Co[row * (long)Nd + col] = v;
      }
    }
  }
}

// ---------------- Chunked complex scan ----------------
// Pass A: per (bloc, chunk, n) local scan from zero state -> carry V
__global__ void scan_carry(const float2* __restrict__ Bu,
                           const float* __restrict__ lam_re, const float* __restrict__ lam_im,
                           float2* __restrict__ V) {
  int idx  = blockIdx.x * 256 + threadIdx.x;  // G*64*512
  int n    = idx & (NDIM - 1);
  int c    = (idx >> 9) & (NCHUNK - 1);
  int bloc = idx >> 15;
  float lr = lam_re[n], li = lam_im[n];
  float xr = 0.f, xi = 0.f;
  long base = ((long)bloc * TSEQ + c * LCHUNK) * NDIM + n;
#pragma unroll 4
  for (int j = 0; j < LCHUNK; j++) {
    float2 bu = Bu[base + (long)j * NDIM];
    float nr = lr * xr - li * xi + bu.x;
    float ni = lr * xi + li * xr + bu.y;
    xr = nr; xi = ni;
  }
  V[idx] = make_float2(xr, xi);
}

// Pass B: per (bloc, n) sequential combine over chunks -> incoming state In[c]
__global__ void scan_combine(const float2* __restrict__ V,
                             const float* __restrict__ lamL_re, const float* __restrict__ lamL_im,
                             const float* __restrict__ x0r, const float* __restrict__ x0i,
                             int b0, float2* __restrict__ In) {
  int idx  = blockIdx.x * 256 + threadIdx.x;  // G*512
  int n    = idx & (NDIM - 1);
  int bloc = idx >> 9;
  int b    = b0 + bloc;
  float lr = lamL_re[n], li = lamL_im[n];
  float sr = x0r[b * NDIM + n], si = x0i[b * NDIM + n];
  long base = (long)bloc * NCHUNK * NDIM + n;
  for (int c = 0; c < NCHUNK; c++) {
    In[base + c * NDIM] = make_float2(sr, si);
    float2 v = V[base + c * NDIM];
    float nr = lr * sr - li * si + v.x;
    float ni = lr * si + li * sr + v.y;
    sr = nr; si = ni;
  }
}

// Pass C: replay local scan with true incoming state; write xs as interleaved bf16
// (A-matrix for GEMM2); write final state (t = T-1) to fs per fs_mode:
//   fs_mode 1: interleaved (re,im) f32 pairs (complex64 memory layout)
//   fs_mode 0: real part only
//   fs_mode -1: skip
__global__ void scan_apply(const float2* __restrict__ Bu, const float2* __restrict__ In,
                           const float* __restrict__ lam_re, const float* __restrict__ lam_im,
                           unsigned int* __restrict__ xsb, float* __restrict__ fs,
                           int b0, int fs_mode) {
  int idx  = blockIdx.x * 256 + threadIdx.x;  // G*64*512
  int n    = idx & (NDIM - 1);
  int c    = (idx >> 9) & (NCHUNK - 1);
  int bloc = idx >> 15;
  float lr = lam_re[n], li = lam_im[n];
  float2 s = In[idx];
  float xr = s.x, xi = s.y;
  long base = ((long)bloc * TSEQ + c * LCHUNK) * NDIM + n;
#pragma unroll 4
  for (int j = 0; j < LCHUNK; j++) {
    float2 bu = Bu[base + (long)j * NDIM];
    float nr = lr * xr - li * xi + bu.x;
    float ni = lr * xi + li * xr + bu.y;
    xr = nr; xi = ni;
    unsigned int p = (unsigned)f2bf(xr) | ((unsigned)f2bf(xi) << 16);
    xsb[base + (long)j * NDIM] = p;
  }
  if (c == NCHUNK - 1 && fs_mode >= 0) {
    int b = b0 + bloc;
    if (fs_mode == 1) {
      fs[(size_t)(b * NDIM + n) * 2]     = xr;
      fs[(size_t)(b * NDIM + n) * 2 + 1] = xi;
    } else {
      fs[(size_t)(b * NDIM + n)] = xr;
    }
  }
}

// ---------------- Host launch ----------------
extern "C" void kernel_launch(void* const* d_in, const int* in_sizes, int n_in,
                              void* d_out, int out_size, void* d_ws, size_t ws_size,
                              hipStream_t stream) {
  const float* x0r       = (const float*)d_in[0];
  const float* x0i       = (const float*)d_in[1];
  const float* u         = (const float*)d_in[2];
  const float* nu_log    = (const float*)d_in[3];
  const float* theta_log = (const float*)d_in[4];
  const float* B_re      = (const float*)d_in[5];
  const float* B_im      = (const float*)d_in[6];
  const float* C_re      = (const float*)d_in[7];
  const float* C_im      = (const float*)d_in[8];
  const float* Dv        = (const float*)d_in[9];

  char* ws = (char*)d_ws;
  size_t off = 0;
  auto alloc = [&](size_t bytes) {
    char* p = ws + off;
    off = (off + bytes + 255) & ~(size_t)255;
    return p;
  };

  float* lam_re  = (float*)alloc(NDIM * 4);
  float* lam_im  = (float*)alloc(NDIM * 4);
  float* gam     = (float*)alloc(NDIM * 4);
  float* lamL_re = (float*)alloc(NDIM * 4);
  float* lamL_im = (float*)alloc(NDIM * 4);
  unsigned short* Bcat = (unsigned short*)alloc((size_t)2 * NDIM * HDIM * 2);
  unsigned short* Ccat = (unsigned short*)alloc((size_t)HDIM * 2 * NDIM * 2);

  // Pick batch group size G so per-group scratch fits in ws.
  const size_t per_batch =
      (size_t)TSEQ * HDIM * 2 +       // u bf16
      (size_t)TSEQ * 2 * NDIM * 4 +   // Bu f32 (interleaved complex)
      (size_t)TSEQ * 2 * NDIM * 2 +   // xs bf16 (interleaved)
      (size_t)2 * NCHUNK * NDIM * 8 + // V, In
      4096;                           // alignment slop
  int G = 16;
  while (G > 1 && off + (size_t)G * per_batch > ws_size) G >>= 1;

  ushort4*      ub  = (ushort4*)alloc((size_t)G * TSEQ * HDIM * 2);
  float*        Bu  = (float*)alloc((size_t)G * TSEQ * 2 * NDIM * 4);
  unsigned int* xsb = (unsigned int*)alloc((size_t)G * TSEQ * NDIM * 4);
  float2*       V   = (float2*)alloc((size_t)G * NCHUNK * NDIM * 8);
  float2*       In  = (float2*)alloc((size_t)G * NCHUNK * NDIM * 8);

  // ---- Output layout detection ----
  // Output 1 (outs) is BATCH*TSEQ*HDIM f32. Whatever remains in out_size is
  // output 0 (final state, complex64 in the reference):
  //   16384 floats -> interleaved (re,im) complex64 view
  //    8192 floats -> real part only (harness astype(f32) of complex drops imag)
  const long outs_elems = (long)BATCH * TSEQ * HDIM;
  long out0 = (long)out_size - outs_elems;
  int fs_mode;
  if (out0 >= 16384)     fs_mode = 1;
  else if (out0 >= 8192) fs_mode = 0;
  else { out0 = 0;       fs_mode = -1; }

  float* fs   = (float*)d_out;
  float* outs = (float*)d_out + out0;

  prep_params<<<1, NDIM, 0, stream>>>(nu_log, theta_log, lam_re, lam_im, gam, lamL_re, lamL_im);
  prep_bcat<<<(2 * NDIM * HDIM) / 256, 256, 0, stream>>>(B_re, B_im, gam, Bcat);
  prep_ccat<<<(HDIM * 2 * NDIM) / 256, 256, 0, stream>>>(C_re, C_im, Ccat);

  for (int b0 = 0; b0 < BATCH; b0 += G) {
    const float* ug = u + (size_t)b0 * TSEQ * HDIM;
    int Mloc = G * TSEQ;
    int n4 = Mloc * HDIM / 4;
    conv_u<<<(n4 + 255) / 256, 256, 0, stream>>>((const float4*)ug, ub, n4);

    dim3 g1(Mloc / 128, (2 * NDIM) / 128);
    gemm_bt<false><<<g1, 256, 0, stream>>>((const unsigned short*)ub, Bcat, Bu,
                                           HDIM, 2 * NDIM, nullptr, nullptr);

    scan_carry<<<(G * NCHUNK * NDIM) / 256, 256, 0, stream>>>(
        (const float2*)Bu, lam_re, lam_im, V);
    scan_combine<<<(G * NDIM) / 256, 256, 0, stream>>>(
        V, lamL_re, lamL_im, x0r, x0i, b0, In);
    scan_apply<<<(G * NCHUNK * NDIM) / 256, 256, 0, stream>>>(
        (const float2*)Bu, In, lam_re, lam_im, xsb, fs, b0, fs_mode);

    dim3 g2(Mloc / 128, HDIM / 128);
    gemm_bt<true><<<g2, 256, 0, stream>>>((const unsigned short*)xsb, Ccat,
                                          outs + (size_t)b0 * TSEQ * HDIM,
                                          2 * NDIM, HDIM, ug, Dv);
  }
}

// Round 3
// 314.336 us; speedup vs baseline: 1.5608x; 1.5608x over previous
//
#include <hip/hip_runtime.h>

// ---------------- Problem constants ----------------
#define BATCH 16
#define TSEQ  4096
#define HDIM  512
#define NDIM  512
#define NCHUNK 64
#define LCHUNK 64   // TSEQ / NCHUNK

using f32x4  = __attribute__((ext_vector_type(4))) float;
using bf16x8 = __attribute__((ext_vector_type(8))) short;

typedef const __attribute__((address_space(1))) void GV;
typedef __attribute__((address_space(3))) void LV;

__device__ __forceinline__ void gload16(const void* g, void* l) {
  __builtin_amdgcn_global_load_lds((GV*)g, (LV*)l, 16, 0, 0);
}
__device__ __forceinline__ unsigned short f2bf(float f) {
  unsigned u = __float_as_uint(f);
  return (unsigned short)((u + 0x7fffu + ((u >> 16) & 1u)) >> 16);
}
__device__ __forceinline__ float bf2f(unsigned short s) {
  return __uint_as_float(((unsigned)s) << 16);
}

// ---------------- Param prep ----------------
__global__ void prep_params(const float* __restrict__ nu_log,
                            const float* __restrict__ theta_log,
                            float* lam_re, float* lam_im, float* gam,
                            float* lamL_re, float* lamL_im) {
  int n = threadIdx.x;
  float en = expf(nu_log[n]);
  float th = expf(theta_log[n]);
  float r  = expf(-en);
  lam_re[n] = r * cosf(th);
  lam_im[n] = r * sinf(th);
  float r2 = expf(-2.f * en);
  gam[n] = sqrtf(fmaxf(1.f - r2, 0.f));
  float rL  = expf(-(float)LCHUNK * en);
  float thL = (float)LCHUNK * th;
  lamL_re[n] = rL * cosf(thL);
  lamL_im[n] = rL * sinf(thL);
}

__global__ void prep_bcat(const float* __restrict__ B_re, const float* __restrict__ B_im,
                          const float* __restrict__ gam, unsigned short* __restrict__ Bcat) {
  int idx = blockIdx.x * 256 + threadIdx.x;
  int h   = idx & (HDIM - 1);
  int row = idx >> 9;
  int n   = row >> 1;
  float g = gam[n];
  float v = (row & 1) ? B_im[n * HDIM + h] : B_re[n * HDIM + h];
  Bcat[idx] = f2bf(g * v);
}

__global__ void prep_ccat(const float* __restrict__ C_re, const float* __restrict__ C_im,
                          unsigned short* __restrict__ Ccat) {
  int idx = blockIdx.x * 256 + threadIdx.x;
  int col = idx & (2 * NDIM - 1);
  int h   = idx >> 10;
  int n   = col >> 1;
  float v = (col & 1) ? -C_im[h * NDIM + n] : C_re[h * NDIM + n];
  Ccat[idx] = f2bf(v);
}

__global__ void conv_u(const float4* __restrict__ u, ushort4* __restrict__ ub, int n4) {
  int idx = blockIdx.x * 256 + threadIdx.x;
  if (idx >= n4) return;
  float4 v = u[idx];
  ushort4 o;
  o.x = f2bf(v.x); o.y = f2bf(v.y); o.z = f2bf(v.z); o.w = f2bf(v.w);
  ub[idx] = o;
}

// ---------------- 256x256 8-phase bf16 MFMA GEMM ----------------
// C[M,Nd] = A[M,K] @ Bm[Nd,K]^T.  OUTBF: write bf16 (GEMM1->Bu).
// else: f32 out + D*u epilogue (GEMM2->outs).
// LDS layout per buffer p (65536 B): [A0|A1|B0|B1] halves of 16384 B each,
// half = 128 rows x 64 k bf16, XOR-swizzled: byte ^= ((row&7)<<4).
template <int K, bool OUTBF>
__global__ __launch_bounds__(512, 2)
void gemm8p(const unsigned short* __restrict__ A,
            const unsigned short* __restrict__ Bm,
            void* __restrict__ Co, int Nb, int Nd,
            const unsigned short* __restrict__ ub,
            const float* __restrict__ Dv) {
  __shared__ char lds[131072];
  const int tid = threadIdx.x;
  const int wid = tid >> 6, lane = tid & 63;
  const int wm = wid >> 2, wn = wid & 3;

  // T1: XCD swizzle (nwg % 8 == 0 guaranteed), bn fastest within chunk.
  int nwg = gridDim.x;
  int bid = blockIdx.x;
  int wg  = (bid & 7) * (nwg >> 3) + (bid >> 3);
  int bn = wg % Nb, bm = wg / Nb;
  const long rowBase = (long)bm * 256;
  const long colBase = (long)bn * 256;

  // Staging source addresses (pre-swizzled so linear LDS dest holds swizzled data):
  // linear LDS slot X = (s*8+wid)*1024 + lane*16 holds global element
  //   row = s*64 + wid*8 + (lane>>3),  col_elem = 8*((lane&7)^(lane>>3))
  const int colE = 8 * ((lane & 7) ^ (lane >> 3));
  const unsigned short* srcA[2][2];
  const unsigned short* srcB[2][2];
#pragma unroll
  for (int a = 0; a < 2; a++)
#pragma unroll
    for (int s = 0; s < 2; s++) {
      long rA = rowBase + a * 128 + s * 64 + wid * 8 + (lane >> 3);
      long rB = colBase + a * 128 + s * 64 + wid * 8 + (lane >> 3);
      srcA[a][s] = A  + rA * K + colE;
      srcB[a][s] = Bm + rB * K + colE;
    }

  f32x4 acc[8][4];
#pragma unroll
  for (int i = 0; i < 8; i++)
#pragma unroll
    for (int j = 0; j < 4; j++) acc[i][j] = (f32x4){0.f, 0.f, 0.f, 0.f};

  // read-side constants
  const int rowAl  = wm * 64 + (lane & 15);
  const int rowBl  = wn * 16 + (lane & 15);
  const int kb0    = (lane >> 4) * 16;
  const int sx     = (lane & 7) << 4;

  bf16x8 af[4][2], b0[2][2], b1[2][2];

  auto STAGE = [&](int p, int which, const unsigned short* s0, const unsigned short* s1) {
    char* d = &lds[p * 65536 + which * 16384 + wid * 1024];
    gload16(s0, d);
    gload16(s1, d + 8192);
  };
  auto LDA = [&](int p, int half) {
#pragma unroll
    for (int i = 0; i < 4; i++)
#pragma unroll
      for (int s = 0; s < 2; s++) {
        int off = p * 65536 + half * 16384 +
                  ((((i * 16 + rowAl) << 7) + s * 64 + kb0) ^ sx);
        af[i][s] = *(const bf16x8*)&lds[off];
      }
  };
  auto LDB = [&](bf16x8 bfr[2][2], int p, int bh) {
#pragma unroll
    for (int j = 0; j < 2; j++)
#pragma unroll
      for (int s = 0; s < 2; s++) {
        int off = p * 65536 + 32768 + bh * 16384 +
                  ((((j * 64 + rowBl) << 7) + s * 64 + kb0) ^ sx);
        bfr[j][s] = *(const bf16x8*)&lds[off];
      }
  };
  auto MM = [&](bf16x8 bfr[2][2], int ah, int bh) {
    __builtin_amdgcn_s_setprio(1);
#pragma unroll
    for (int i = 0; i < 4; i++)
#pragma unroll
      for (int j = 0; j < 2; j++)
#pragma unroll
        for (int s = 0; s < 2; s++)
          acc[ah * 4 + i][bh * 2 + j] = __builtin_amdgcn_mfma_f32_16x16x32_bf16(
              af[i][s], bfr[j][s], acc[ah * 4 + i][bh * 2 + j], 0, 0, 0);
    __builtin_amdgcn_s_setprio(0);
  };

#define BAR()   asm volatile("s_barrier" ::: "memory")
#define LGKM0() asm volatile("s_waitcnt lgkmcnt(0)" ::: "memory")

  const int NT = K / 64;
  // Prologue: stage tile 0 (order A0,B0,B1,A1), allow A1 (last 2 loads) in flight.
  STAGE(0, 0, srcA[0][0], srcA[0][1]);
  STAGE(0, 2, srcB[0][0], srcB[0][1]);
  STAGE(0, 3, srcB[1][0], srcB[1][1]);
  STAGE(0, 1, srcA[1][0], srcA[1][1]);
  asm volatile("s_waitcnt vmcnt(2)" ::: "memory");
  BAR();

#pragma unroll 1
  for (int t = 0; t < NT - 1; t++) {
    const int p = t & 1, q = p ^ 1;
    const int ko = (t + 1) * 64;
    // ph0: quadrant (A0,B0); stage next A0
    LDA(p, 0); LDB(b0, p, 0);
    STAGE(q, 0, srcA[0][0] + ko, srcA[0][1] + ko);
    BAR(); LGKM0();
    MM(b0, 0, 0);
    BAR();
    // ph1: (A0,B1); stage next B0; gate this tile's A1 (issued 2 half-tiles ago)
    LDB(b1, p, 1);
    STAGE(q, 2, srcB[0][0] + ko, srcB[0][1] + ko);
    BAR(); LGKM0();
    MM(b1, 0, 1);
    asm volatile("s_waitcnt vmcnt(4)" ::: "memory");
    BAR();
    // ph2: (A1,B1); stage next B1
    LDA(p, 1);
    STAGE(q, 3, srcB[1][0] + ko, srcB[1][1] + ko);
    BAR(); LGKM0();
    MM(b1, 1, 1);
    BAR();
    // ph3: (A1,B0); stage next A1; gate next tile's A0,B0,B1 (leave A1' in flight)
    LDB(b0, p, 0);
    STAGE(q, 1, srcA[1][0] + ko, srcA[1][1] + ko);
    BAR(); LGKM0();
    MM(b0, 1, 0);
    asm volatile("s_waitcnt vmcnt(2)" ::: "memory");
    BAR();
  }
  // Last tile: no staging; drain A1 before ph2.
  {
    const int p = (NT - 1) & 1;
    LDA(p, 0); LDB(b0, p, 0);
    BAR(); LGKM0();
    MM(b0, 0, 0);
    BAR();
    LDB(b1, p, 1);
    BAR(); LGKM0();
    MM(b1, 0, 1);
    asm volatile("s_waitcnt vmcnt(0)" ::: "memory");
    BAR();
    LDA(p, 1);
    BAR(); LGKM0();
    MM(b1, 1, 1);
    BAR();
    LDB(b0, p, 0);
    BAR(); LGKM0();
    MM(b0, 1, 0);
  }
#undef BAR
#undef LGKM0

  // Epilogue
  const int cc = lane & 15, r4 = (lane >> 4) * 4;
#pragma unroll
  for (int ig = 0; ig < 8; ig++) {
    long row = rowBase + (ig & 3) * 16 + wm * 64 + (ig >> 2) * 128 + r4;
#pragma unroll
    for (int j = 0; j < 4; j++) {
      long col = colBase + j * 64 + wn * 16 + cc;
      if (OUTBF) {
        unsigned short* Cb = (unsigned short*)Co;
#pragma unroll
        for (int r = 0; r < 4; r++)
          Cb[(row + r) * (long)Nd + col] = f2bf(acc[ig][j][r]);
      } else {
        float* Cf = (float*)Co;
        float d = Dv[col];
#pragma unroll
        for (int r = 0; r < 4; r++)
          Cf[(row + r) * (long)Nd + col] =
              acc[ig][j][r] + d * bf2f(ub[(row + r) * (long)Nd + col]);
      }
    }
  }
}

// ---------------- Chunked complex scan (Bu packed bf16 re|im) ----------------
__global__ void scan_carry(const unsigned* __restrict__ Bu,
                           const float* __restrict__ lam_re, const float* __restrict__ lam_im,
                           float2* __restrict__ V) {
  int idx  = blockIdx.x * 256 + threadIdx.x;
  int n    = idx & (NDIM - 1);
  int c    = (idx >> 9) & (NCHUNK - 1);
  int bloc = idx >> 15;
  float lr = lam_re[n], li = lam_im[n];
  float xr = 0.f, xi = 0.f;
  long base = ((long)bloc * TSEQ + c * LCHUNK) * NDIM + n;
#pragma unroll 4
  for (int j = 0; j < LCHUNK; j++) {
    unsigned pv = Bu[base + (long)j * NDIM];
    float br = bf2f((unsigned short)(pv & 0xffff));
    float bi = bf2f((unsigned short)(pv >> 16));
    float nr = lr * xr - li * xi + br;
    float ni = lr * xi + li * xr + bi;
    xr = nr; xi = ni;
  }
  V[idx] = make_float2(xr, xi);
}

__global__ void scan_combine(const float2* __restrict__ V,
                             const float* __restrict__ lamL_re, const float* __restrict__ lamL_im,
                             const float* __restrict__ x0r, const float* __restrict__ x0i,
                             int b0, float2* __restrict__ In) {
  int idx  = blockIdx.x * 256 + threadIdx.x;
  int n    = idx & (NDIM - 1);
  int bloc = idx >> 9;
  int b    = b0 + bloc;
  float lr = lamL_re[n], li = lamL_im[n];
  float sr = x0r[b * NDIM + n], si = x0i[b * NDIM + n];
  long base = (long)bloc * NCHUNK * NDIM + n;
  for (int c = 0; c < NCHUNK; c++) {
    In[base + c * NDIM] = make_float2(sr, si);
    float2 v = V[base + c * NDIM];
    float nr = lr * sr - li * si + v.x;
    float ni = lr * si + li * sr + v.y;
    sr = nr; si = ni;
  }
}

__global__ void scan_apply(const unsigned* __restrict__ Bu, const float2* __restrict__ In,
                           const float* __restrict__ lam_re, const float* __restrict__ lam_im,
                           unsigned int* __restrict__ xsb, float* __restrict__ fs,
                           int b0, int fs_mode) {
  int idx  = blockIdx.x * 256 + threadIdx.x;
  int n    = idx & (NDIM - 1);
  int c    = (idx >> 9) & (NCHUNK - 1);
  int bloc = idx >> 15;
  float lr = lam_re[n], li = lam_im[n];
  float2 s = In[idx];
  float xr = s.x, xi = s.y;
  long base = ((long)bloc * TSEQ + c * LCHUNK) * NDIM + n;
#pragma unroll 4
  for (int j = 0; j < LCHUNK; j++) {
    unsigned pv = Bu[base + (long)j * NDIM];
    float br = bf2f((unsigned short)(pv & 0xffff));
    float bi = bf2f((unsigned short)(pv >> 16));
    float nr = lr * xr - li * xi + br;
    float ni = lr * xi + li * xr + bi;
    xr = nr; xi = ni;
    xsb[base + (long)j * NDIM] = (unsigned)f2bf(xr) | ((unsigned)f2bf(xi) << 16);
  }
  if (c == NCHUNK - 1 && fs_mode >= 0) {
    int b = b0 + bloc;
    if (fs_mode == 1) {
      fs[(size_t)(b * NDIM + n) * 2]     = xr;
      fs[(size_t)(b * NDIM + n) * 2 + 1] = xi;
    } else {
      fs[(size_t)(b * NDIM + n)] = xr;
    }
  }
}

// ---------------- Host launch ----------------
extern "C" void kernel_launch(void* const* d_in, const int* in_sizes, int n_in,
                              void* d_out, int out_size, void* d_ws, size_t ws_size,
                              hipStream_t stream) {
  const float* x0r       = (const float*)d_in[0];
  const float* x0i       = (const float*)d_in[1];
  const float* u         = (const float*)d_in[2];
  const float* nu_log    = (const float*)d_in[3];
  const float* theta_log = (const float*)d_in[4];
  const float* B_re      = (const float*)d_in[5];
  const float* B_im      = (const float*)d_in[6];
  const float* C_re      = (const float*)d_in[7];
  const float* C_im      = (const float*)d_in[8];
  const float* Dv        = (const float*)d_in[9];

  char* ws = (char*)d_ws;
  size_t off = 0;
  auto alloc = [&](size_t bytes) {
    char* p = ws + off;
    off = (off + bytes + 255) & ~(size_t)255;
    return p;
  };

  float* lam_re  = (float*)alloc(NDIM * 4);
  float* lam_im  = (float*)alloc(NDIM * 4);
  float* gam     = (float*)alloc(NDIM * 4);
  float* lamL_re = (float*)alloc(NDIM * 4);
  float* lamL_im = (float*)alloc(NDIM * 4);
  unsigned short* Bcat = (unsigned short*)alloc((size_t)2 * NDIM * HDIM * 2);
  unsigned short* Ccat = (unsigned short*)alloc((size_t)HDIM * 2 * NDIM * 2);

  const size_t per_batch =
      (size_t)TSEQ * HDIM * 2 +       // u bf16
      (size_t)TSEQ * NDIM * 4 +       // Bu packed bf16 (re|im)
      (size_t)TSEQ * NDIM * 4 +       // xs packed bf16
      (size_t)2 * NCHUNK * NDIM * 8 + // V, In
      4096;
  int G = 16;
  while (G > 1 && off + (size_t)G * per_batch > ws_size) G >>= 1;

  ushort4*      ub  = (ushort4*)alloc((size_t)G * TSEQ * HDIM * 2);
  unsigned*     Bu  = (unsigned*)alloc((size_t)G * TSEQ * NDIM * 4);
  unsigned int* xsb = (unsigned int*)alloc((size_t)G * TSEQ * NDIM * 4);
  float2*       V   = (float2*)alloc((size_t)G * NCHUNK * NDIM * 8);
  float2*       In  = (float2*)alloc((size_t)G * NCHUNK * NDIM * 8);

  const long outs_elems = (long)BATCH * TSEQ * HDIM;
  long out0 = (long)out_size - outs_elems;
  int fs_mode;
  if (out0 >= 16384)     fs_mode = 1;
  else if (out0 >= 8192) fs_mode = 0;
  else { out0 = 0;       fs_mode = -1; }

  float* fs   = (float*)d_out;
  float* outs = (float*)d_out + out0;

  prep_params<<<1, NDIM, 0, stream>>>(nu_log, theta_log, lam_re, lam_im, gam, lamL_re, lamL_im);
  prep_bcat<<<(2 * NDIM * HDIM) / 256, 256, 0, stream>>>(B_re, B_im, gam, Bcat);
  prep_ccat<<<(HDIM * 2 * NDIM) / 256, 256, 0, stream>>>(C_re, C_im, Ccat);

  for (int b0 = 0; b0 < BATCH; b0 += G) {
    const float* ug = u + (size_t)b0 * TSEQ * HDIM;
    int Mloc = G * TSEQ;
    int n4 = Mloc * HDIM / 4;
    conv_u<<<(n4 + 255) / 256, 256, 0, stream>>>((const float4*)ug, ub, n4);

    // GEMM1: Bu[M, 2N] (bf16 packed) = ub[M,512] @ Bcat[1024,512]^T
    int nwg1 = (Mloc / 256) * 4;
    gemm8p<512, true><<<nwg1, 512, 0, stream>>>(
        (const unsigned short*)ub, Bcat, Bu, 4, 2 * NDIM, nullptr, nullptr);

    scan_carry<<<(G * NCHUNK * NDIM) / 256, 256, 0, stream>>>(Bu, lam_re, lam_im, V);
    scan_combine<<<(G * NDIM) / 256, 256, 0, stream>>>(
        V, lamL_re, lamL_im, x0r, x0i, b0, In);
    scan_apply<<<(G * NCHUNK * NDIM) / 256, 256, 0, stream>>>(
        Bu, In, lam_re, lam_im, xsb, fs, b0, fs_mode);

    // GEMM2: outs[M,512] = xsb[M,1024] @ Ccat[512,1024]^T + D*u
    int nwg2 = (Mloc / 256) * 2;
    gemm8p<1024, false><<<nwg2, 512, 0, stream>>>(
        (const unsigned short*)xsb, Ccat, outs + (size_t)b0 * TSEQ * HDIM,
        2, HDIM, (const unsigned short*)ub, Dv);
  }
}

// Round 4
// 309.539 us; speedup vs baseline: 1.5850x; 1.0155x over previous
//
#include <hip/hip_runtime.h>

// ---------------- Problem constants ----------------
#define BATCH 16
#define TSEQ  4096
#define HDIM  512
#define NDIM  512
#define NCHUNK 64
#define LCHUNK 64   // TSEQ / NCHUNK

using f32x4  = __attribute__((ext_vector_type(4))) float;
using bf16x8 = __attribute__((ext_vector_type(8))) short;

typedef const __attribute__((address_space(1))) void GV;
typedef __attribute__((address_space(3))) void LV;

__device__ __forceinline__ void gload16(const void* g, void* l) {
  __builtin_amdgcn_global_load_lds((GV*)g, (LV*)l, 16, 0, 0);
}
__device__ __forceinline__ unsigned short f2bf(float f) {
  unsigned u = __float_as_uint(f);
  return (unsigned short)((u + 0x7fffu + ((u >> 16) & 1u)) >> 16);
}
__device__ __forceinline__ float bf2f(unsigned short s) {
  return __uint_as_float(((unsigned)s) << 16);
}

// ---------------- Param prep ----------------
__global__ void prep_params(const float* __restrict__ nu_log,
                            const float* __restrict__ theta_log,
                            float* lam_re, float* lam_im, float* gam,
                            float* lamL_re, float* lamL_im) {
  int n = threadIdx.x;
  float en = expf(nu_log[n]);
  float th = expf(theta_log[n]);
  float r  = expf(-en);
  lam_re[n] = r * cosf(th);
  lam_im[n] = r * sinf(th);
  float r2 = expf(-2.f * en);
  gam[n] = sqrtf(fmaxf(1.f - r2, 0.f));
  float rL  = expf(-(float)LCHUNK * en);
  float thL = (float)LCHUNK * th;
  lamL_re[n] = rL * cosf(thL);
  lamL_im[n] = rL * sinf(thL);
}

__global__ void prep_bcat(const float* __restrict__ B_re, const float* __restrict__ B_im,
                          const float* __restrict__ gam, unsigned short* __restrict__ Bcat) {
  int idx = blockIdx.x * 256 + threadIdx.x;
  int h   = idx & (HDIM - 1);
  int row = idx >> 9;
  int n   = row >> 1;
  float g = gam[n];
  float v = (row & 1) ? B_im[n * HDIM + h] : B_re[n * HDIM + h];
  Bcat[idx] = f2bf(g * v);
}

__global__ void prep_ccat(const float* __restrict__ C_re, const float* __restrict__ C_im,
                          unsigned short* __restrict__ Ccat) {
  int idx = blockIdx.x * 256 + threadIdx.x;
  int col = idx & (2 * NDIM - 1);
  int h   = idx >> 10;
  int n   = col >> 1;
  float v = (col & 1) ? -C_im[h * NDIM + n] : C_re[h * NDIM + n];
  Ccat[idx] = f2bf(v);
}

__global__ void conv_u(const float4* __restrict__ u, ushort4* __restrict__ ub, int n4) {
  int idx = blockIdx.x * 256 + threadIdx.x;
  if (idx >= n4) return;
  float4 v = u[idx];
  ushort4 o;
  o.x = f2bf(v.x); o.y = f2bf(v.y); o.z = f2bf(v.z); o.w = f2bf(v.w);
  ub[idx] = o;
}

// ---------------- 256x256 bf16 MFMA GEMM, 3-phase/K-tile, counted vmcnt ----------------
// C[M,Nd] = A[M,K] @ Bm[Nd,K]^T.  OUTBF: write bf16 (GEMM1->Bu),
// else f32 out + D*u epilogue (GEMM2->outs).
// LDS per buffer (65536 B): slots [A0|A1|B0|B1] x 16384 B, half = 128 rows x 64 k,
// XOR-swizzled byte ^= ((row&7)<<4) via pre-swizzled global source.
// Staging: slot staged exactly 4 phases before its first ds_read; gates give
// every load a 3-phase landing window (m218/T4 discipline).
template <int K, bool OUTBF>
__global__ __launch_bounds__(512, 2)
void gemm8p(const unsigned short* __restrict__ A,
            const unsigned short* __restrict__ Bm,
            void* __restrict__ Co, int Nb, int Nd,
            const unsigned short* __restrict__ ub,
            const float* __restrict__ Dv) {
  __shared__ char lds[131072];
  const int tid = threadIdx.x;
  const int wid = tid >> 6, lane = tid & 63;
  const int wm = wid >> 2, wn = wid & 3;

  // T1: XCD swizzle (nwg % 8 == 0), bn fastest within an XCD's chunk.
  int nwg = gridDim.x;
  int bid = blockIdx.x;
  int wg  = (bid & 7) * (nwg >> 3) + (bid >> 3);
  int bn = wg % Nb, bm = wg / Nb;
  const long rowBase = (long)bm * 256;
  const long colBase = (long)bn * 256;

  // Pre-swizzled global sources: linear LDS slot holds swizzled data.
  const int colE = 8 * ((lane & 7) ^ (lane >> 3));
  const unsigned short* srcA[2][2];
  const unsigned short* srcB[2][2];
#pragma unroll
  for (int a = 0; a < 2; a++)
#pragma unroll
    for (int s = 0; s < 2; s++) {
      long rA = rowBase + a * 128 + s * 64 + wid * 8 + (lane >> 3);
      long rB = colBase + a * 128 + s * 64 + wid * 8 + (lane >> 3);
      srcA[a][s] = A  + rA * K + colE;
      srcB[a][s] = Bm + rB * K + colE;
    }

  f32x4 acc[8][4];
#pragma unroll
  for (int i = 0; i < 8; i++)
#pragma unroll
    for (int j = 0; j < 4; j++) acc[i][j] = (f32x4){0.f, 0.f, 0.f, 0.f};

  const int rowAl = wm * 64 + (lane & 15);
  const int rowBl = wn * 16 + (lane & 15);
  const int kb0   = (lane >> 4) * 16;
  const int sx    = (lane & 7) << 4;

  bf16x8 af[4][2], b0[2][2], b1[2][2];

  auto STAGE = [&](int p, int which, const unsigned short* s0, const unsigned short* s1) {
    char* d = &lds[p * 65536 + which * 16384 + wid * 1024];
    gload16(s0, d);
    gload16(s1, d + 8192);
  };
  auto LDA = [&](int p, int half) {
#pragma unroll
    for (int i = 0; i < 4; i++)
#pragma unroll
      for (int s = 0; s < 2; s++) {
        int off = p * 65536 + half * 16384 +
                  ((((i * 16 + rowAl) << 7) + s * 64 + kb0) ^ sx);
        af[i][s] = *(const bf16x8*)&lds[off];
      }
  };
  auto LDB = [&](bf16x8 bfr[2][2], int p, int bh) {
#pragma unroll
    for (int j = 0; j < 2; j++)
#pragma unroll
      for (int s = 0; s < 2; s++) {
        int off = p * 65536 + 32768 + bh * 16384 +
                  ((((j * 64 + rowBl) << 7) + s * 64 + kb0) ^ sx);
        bfr[j][s] = *(const bf16x8*)&lds[off];
      }
  };
  auto MM = [&](bf16x8 bfr[2][2], int ah, int bh) {
    __builtin_amdgcn_s_setprio(1);
#pragma unroll
    for (int i = 0; i < 4; i++)
#pragma unroll
      for (int j = 0; j < 2; j++)
#pragma unroll
        for (int s = 0; s < 2; s++)
          acc[ah * 4 + i][bh * 2 + j] = __builtin_amdgcn_mfma_f32_16x16x32_bf16(
              af[i][s], bfr[j][s], acc[ah * 4 + i][bh * 2 + j], 0, 0, 0);
    __builtin_amdgcn_s_setprio(0);
  };

#define BAR()   asm volatile("s_barrier" ::: "memory")
#define LGKM0() do { asm volatile("s_waitcnt lgkmcnt(0)" ::: "memory"); \
                     __builtin_amdgcn_sched_barrier(0); } while (0)
#define VM(n)   asm volatile("s_waitcnt vmcnt(" #n ")" ::: "memory")

  const int NT = K / 64;
  // Prologue: stage tile 0 in read order A0,B0 (4 loads) then B1, A1.
  STAGE(0, 0, srcA[0][0], srcA[0][1]);
  STAGE(0, 2, srcB[0][0], srcB[0][1]);
  STAGE(0, 3, srcB[1][0], srcB[1][1]);
  STAGE(0, 1, srcA[1][0], srcA[1][1]);
  VM(4);  // A0,B0 landed; B1,A1 in flight
  BAR();

#pragma unroll 1
  for (int t = 0; t < NT - 1; t++) {
    const int p = t & 1, q = p ^ 1;
    const int ko = (t + 1) * 64;
    // ph0: read A0,B0 | stage next A0,B0 | MFMA (A0,B0) | gate B1 (3-ph window)
    LDA(p, 0); LDB(b0, p, 0);
    STAGE(q, 0, srcA[0][0] + ko, srcA[0][1] + ko);
    STAGE(q, 2, srcB[0][0] + ko, srcB[0][1] + ko);
    BAR(); LGKM0();
    MM(b0, 0, 0);
    VM(6);
    BAR();
    // ph1: read B1 | stage next B1 | MFMA (A0,B1) | gate A1 (3-ph window)
    LDB(b1, p, 1);
    STAGE(q, 3, srcB[1][0] + ko, srcB[1][1] + ko);
    BAR(); LGKM0();
    MM(b1, 0, 1);
    VM(6);
    BAR();
    // ph2+3: read A1 | stage next A1 | MFMA (A1,B1)+(A1,B0) | gate next A0,B0
    LDA(p, 1);
    STAGE(q, 1, srcA[1][0] + ko, srcA[1][1] + ko);
    BAR(); LGKM0();
    MM(b1, 1, 1);
    MM(b0, 1, 0);
    VM(4);
    BAR();
  }
  // Final tile: no staging; drain remaining B1,A1 progressively.
  {
    const int p = (NT - 1) & 1;
    LDA(p, 0); LDB(b0, p, 0);
    BAR(); LGKM0();
    MM(b0, 0, 0);
    VM(2);  // B1 landed
    BAR();
    LDB(b1, p, 1);
    BAR(); LGKM0();
    MM(b1, 0, 1);
    VM(0);  // A1 landed
    BAR();
    LDA(p, 1);
    BAR(); LGKM0();
    MM(b1, 1, 1);
    MM(b0, 1, 0);
  }
#undef BAR
#undef LGKM0
#undef VM

  // Epilogue
  const int cc = lane & 15, r4 = (lane >> 4) * 4;
#pragma unroll
  for (int ig = 0; ig < 8; ig++) {
    long row = rowBase + (ig & 3) * 16 + wm * 64 + (ig >> 2) * 128 + r4;
#pragma unroll
    for (int j = 0; j < 4; j++) {
      long col = colBase + j * 64 + wn * 16 + cc;
      if (OUTBF) {
        unsigned short* Cb = (unsigned short*)Co;
#pragma unroll
        for (int r = 0; r < 4; r++)
          Cb[(row + r) * (long)Nd + col] = f2bf(acc[ig][j][r]);
      } else {
        float* Cf = (float*)Co;
        float d = Dv[col];
#pragma unroll
        for (int r = 0; r < 4; r++)
          Cf[(row + r) * (long)Nd + col] =
              acc[ig][j][r] + d * bf2f(ub[(row + r) * (long)Nd + col]);
      }
    }
  }
}

// ---------------- Chunked complex scan (Bu packed bf16 re|im) ----------------
__global__ void scan_carry(const unsigned* __restrict__ Bu,
                           const float* __restrict__ lam_re, const float* __restrict__ lam_im,
                           float2* __restrict__ V) {
  int idx  = blockIdx.x * 256 + threadIdx.x;
  int n    = idx & (NDIM - 1);
  int c    = (idx >> 9) & (NCHUNK - 1);
  int bloc = idx >> 15;
  float lr = lam_re[n], li = lam_im[n];
  float xr = 0.f, xi = 0.f;
  long base = ((long)bloc * TSEQ + c * LCHUNK) * NDIM + n;
#pragma unroll 4
  for (int j = 0; j < LCHUNK; j++) {
    unsigned pv = Bu[base + (long)j * NDIM];
    float br = bf2f((unsigned short)(pv & 0xffff));
    float bi = bf2f((unsigned short)(pv >> 16));
    float nr = lr * xr - li * xi + br;
    float ni = lr * xi + li * xr + bi;
    xr = nr; xi = ni;
  }
  V[idx] = make_float2(xr, xi);
}

__global__ void scan_combine(const float2* __restrict__ V,
                             const float* __restrict__ lamL_re, const float* __restrict__ lamL_im,
                             const float* __restrict__ x0r, const float* __restrict__ x0i,
                             int b0, float2* __restrict__ In) {
  int idx  = blockIdx.x * 256 + threadIdx.x;
  int n    = idx & (NDIM - 1);
  int bloc = idx >> 9;
  int b    = b0 + bloc;
  float lr = lamL_re[n], li = lamL_im[n];
  float sr = x0r[b * NDIM + n], si = x0i[b * NDIM + n];
  long base = (long)bloc * NCHUNK * NDIM + n;
  for (int c = 0; c < NCHUNK; c++) {
    In[base + c * NDIM] = make_float2(sr, si);
    float2 v = V[base + c * NDIM];
    float nr = lr * sr - li * si + v.x;
    float ni = lr * si + li * sr + v.y;
    sr = nr; si = ni;
  }
}

__global__ void scan_apply(const unsigned* __restrict__ Bu, const float2* __restrict__ In,
                           const float* __restrict__ lam_re, const float* __restrict__ lam_im,
                           unsigned int* __restrict__ xsb, float* __restrict__ fs,
                           int b0, int fs_mode) {
  int idx  = blockIdx.x * 256 + threadIdx.x;
  int n    = idx & (NDIM - 1);
  int c    = (idx >> 9) & (NCHUNK - 1);
  int bloc = idx >> 15;
  float lr = lam_re[n], li = lam_im[n];
  float2 s = In[idx];
  float xr = s.x, xi = s.y;
  long base = ((long)bloc * TSEQ + c * LCHUNK) * NDIM + n;
#pragma unroll 4
  for (int j = 0; j < LCHUNK; j++) {
    unsigned pv = Bu[base + (long)j * NDIM];
    float br = bf2f((unsigned short)(pv & 0xffff));
    float bi = bf2f((unsigned short)(pv >> 16));
    float nr = lr * xr - li * xi + br;
    float ni = lr * xi + li * xr + bi;
    xr = nr; xi = ni;
    xsb[base + (long)j * NDIM] = (unsigned)f2bf(xr) | ((unsigned)f2bf(xi) << 16);
  }
  if (c == NCHUNK - 1 && fs_mode >= 0) {
    int b = b0 + bloc;
    if (fs_mode == 1) {
      fs[(size_t)(b * NDIM + n) * 2]     = xr;
      fs[(size_t)(b * NDIM + n) * 2 + 1] = xi;
    } else {
      fs[(size_t)(b * NDIM + n)] = xr;
    }
  }
}

// ---------------- Host launch ----------------
extern "C" void kernel_launch(void* const* d_in, const int* in_sizes, int n_in,
                              void* d_out, int out_size, void* d_ws, size_t ws_size,
                              hipStream_t stream) {
  const float* x0r       = (const float*)d_in[0];
  const float* x0i       = (const float*)d_in[1];
  const float* u         = (const float*)d_in[2];
  const float* nu_log    = (const float*)d_in[3];
  const float* theta_log = (const float*)d_in[4];
  const float* B_re      = (const float*)d_in[5];
  const float* B_im      = (const float*)d_in[6];
  const float* C_re      = (const float*)d_in[7];
  const float* C_im      = (const float*)d_in[8];
  const float* Dv        = (const float*)d_in[9];

  char* ws = (char*)d_ws;
  size_t off = 0;
  auto alloc = [&](size_t bytes) {
    char* p = ws + off;
    off = (off + bytes + 255) & ~(size_t)255;
    return p;
  };

  float* lam_re  = (float*)alloc(NDIM * 4);
  float* lam_im  = (float*)alloc(NDIM * 4);
  float* gam     = (float*)alloc(NDIM * 4);
  float* lamL_re = (float*)alloc(NDIM * 4);
  float* lamL_im = (float*)alloc(NDIM * 4);
  unsigned short* Bcat = (unsigned short*)alloc((size_t)2 * NDIM * HDIM * 2);
  unsigned short* Ccat = (unsigned short*)alloc((size_t)HDIM * 2 * NDIM * 2);

  const size_t per_batch =
      (size_t)TSEQ * HDIM * 2 +       // u bf16
      (size_t)TSEQ * NDIM * 4 +       // Bu packed bf16 (re|im)
      (size_t)TSEQ * NDIM * 4 +       // xs packed bf16
      (size_t)2 * NCHUNK * NDIM * 8 + // V, In
      4096;
  int G = 16;
  while (G > 1 && off + (size_t)G * per_batch > ws_size) G >>= 1;

  ushort4*      ub  = (ushort4*)alloc((size_t)G * TSEQ * HDIM * 2);
  unsigned*     Bu  = (unsigned*)alloc((size_t)G * TSEQ * NDIM * 4);
  unsigned int* xsb = (unsigned int*)alloc((size_t)G * TSEQ * NDIM * 4);
  float2*       V   = (float2*)alloc((size_t)G * NCHUNK * NDIM * 8);
  float2*       In  = (float2*)alloc((size_t)G * NCHUNK * NDIM * 8);

  const long outs_elems = (long)BATCH * TSEQ * HDIM;
  long out0 = (long)out_size - outs_elems;
  int fs_mode;
  if (out0 >= 16384)     fs_mode = 1;
  else if (out0 >= 8192) fs_mode = 0;
  else { out0 = 0;       fs_mode = -1; }

  float* fs   = (float*)d_out;
  float* outs = (float*)d_out + out0;

  prep_params<<<1, NDIM, 0, stream>>>(nu_log, theta_log, lam_re, lam_im, gam, lamL_re, lamL_im);
  prep_bcat<<<(2 * NDIM * HDIM) / 256, 256, 0, stream>>>(B_re, B_im, gam, Bcat);
  prep_ccat<<<(HDIM * 2 * NDIM) / 256, 256, 0, stream>>>(C_re, C_im, Ccat);

  for (int b0 = 0; b0 < BATCH; b0 += G) {
    const float* ug = u + (size_t)b0 * TSEQ * HDIM;
    int Mloc = G * TSEQ;
    int n4 = Mloc * HDIM / 4;
    conv_u<<<(n4 + 255) / 256, 256, 0, stream>>>((const float4*)ug, ub, n4);

    // GEMM1: Bu[M, 2N] (bf16 packed) = ub[M,512] @ Bcat[1024,512]^T
    int nwg1 = (Mloc / 256) * 4;
    gemm8p<512, true><<<nwg1, 512, 0, stream>>>(
        (const unsigned short*)ub, Bcat, Bu, 4, 2 * NDIM, nullptr, nullptr);

    scan_carry<<<(G * NCHUNK * NDIM) / 256, 256, 0, stream>>>(Bu, lam_re, lam_im, V);
    scan_combine<<<(G * NDIM) / 256, 256, 0, stream>>>(
        V, lamL_re, lamL_im, x0r, x0i, b0, In);
    scan_apply<<<(G * NCHUNK * NDIM) / 256, 256, 0, stream>>>(
        Bu, In, lam_re, lam_im, xsb, fs, b0, fs_mode);

    // GEMM2: outs[M,512] = xsb[M,1024] @ Ccat[512,1024]^T + D*u
    int nwg2 = (Mloc / 256) * 2;
    gemm8p<1024, false><<<nwg2, 512, 0, stream>>>(
        (const unsigned short*)xsb, Ccat, outs + (size_t)b0 * TSEQ * HDIM,
        2, HDIM, (const unsigned short*)ub, Dv);
  }
}

// Round 5
// 300.674 us; speedup vs baseline: 1.6318x; 1.0295x over previous
//
#include <hip/hip_runtime.h>

// ---------------- Problem constants ----------------
#define BATCH 16
#define TSEQ  4096
#define HDIM  512
#define NDIM  512
#define NCHUNK 64
#define LCHUNK 64   // TSEQ / NCHUNK

using f32x4  = __attribute__((ext_vector_type(4))) float;
using bf16x8 = __attribute__((ext_vector_type(8))) short;

typedef const __attribute__((address_space(1))) void GV;
typedef __attribute__((address_space(3))) void LV;

__device__ __forceinline__ void gload16(const void* g, void* l) {
  __builtin_amdgcn_global_load_lds((GV*)g, (LV*)l, 16, 0, 0);
}
__device__ __forceinline__ unsigned short f2bf(float f) {
  unsigned u = __float_as_uint(f);
  return (unsigned short)((u + 0x7fffu + ((u >> 16) & 1u)) >> 16);
}
__device__ __forceinline__ float bf2f(unsigned short s) {
  return __uint_as_float(((unsigned)s) << 16);
}

// ---------------- Param prep ----------------
__global__ void prep_params(const float* __restrict__ nu_log,
                            const float* __restrict__ theta_log,
                            float* lam_re, float* lam_im, float* gam,
                            float* lamL_re, float* lamL_im) {
  int n = threadIdx.x;
  float en = expf(nu_log[n]);
  float th = expf(theta_log[n]);
  float r  = expf(-en);
  lam_re[n] = r * cosf(th);
  lam_im[n] = r * sinf(th);
  float r2 = expf(-2.f * en);
  gam[n] = sqrtf(fmaxf(1.f - r2, 0.f));
  float rL  = expf(-(float)LCHUNK * en);
  float thL = (float)LCHUNK * th;
  lamL_re[n] = rL * cosf(thL);
  lamL_im[n] = rL * sinf(thL);
}

__global__ void prep_bcat(const float* __restrict__ B_re, const float* __restrict__ B_im,
                          const float* __restrict__ gam, unsigned short* __restrict__ Bcat) {
  int idx = blockIdx.x * 256 + threadIdx.x;
  int h   = idx & (HDIM - 1);
  int row = idx >> 9;
  int n   = row >> 1;
  float g = gam[n];
  float v = (row & 1) ? B_im[n * HDIM + h] : B_re[n * HDIM + h];
  Bcat[idx] = f2bf(g * v);
}

__global__ void prep_ccat(const float* __restrict__ C_re, const float* __restrict__ C_im,
                          unsigned short* __restrict__ Ccat) {
  int idx = blockIdx.x * 256 + threadIdx.x;
  int col = idx & (2 * NDIM - 1);
  int h   = idx >> 10;
  int n   = col >> 1;
  float v = (col & 1) ? -C_im[h * NDIM + n] : C_re[h * NDIM + n];
  Ccat[idx] = f2bf(v);
}

__global__ void conv_u(const float4* __restrict__ u, ushort4* __restrict__ ub, int n4) {
  int idx = blockIdx.x * 256 + threadIdx.x;
  if (idx >= n4) return;
  float4 v = u[idx];
  ushort4 o;
  o.x = f2bf(v.x); o.y = f2bf(v.y); o.z = f2bf(v.z); o.w = f2bf(v.w);
  ub[idx] = o;
}

// ---------------- 256x256 bf16 MFMA GEMM, 4-phase/K-tile, 1 barrier/phase ----------------
// C[M,Nd] = A[M,K] @ Bm[Nd,K]^T.  OUTBF: write bf16 (GEMM1->Bu),
// else f32 out + D*u epilogue (GEMM2->outs).
// LDS per buffer (65536 B): slots [A0|A1|B0|B1] x 16384 B, half = 128 rows x 64 k,
// XOR-swizzled byte ^= ((row&7)<<4) via pre-swizzled global source.
// Schedule: 4 phases/tile, ONE barrier per phase, counted VM(4) gates at
// ph0/ph1/ph3 ends; ds_read->MFMA waits left to the compiler (fine-grained
// lgkmcnt). Slot-reuse gap >= 5 barriers -> 1-barrier/phase is race-free.
template <int K, bool OUTBF>
__global__ __launch_bounds__(512, 2)
void gemm8p(const unsigned short* __restrict__ A,
            const unsigned short* __restrict__ Bm,
            void* __restrict__ Co, int Nb, int Nd,
            const unsigned short* __restrict__ ub,
            const float* __restrict__ Dv) {
  __shared__ char lds[131072];
  const int tid = threadIdx.x;
  const int wid = tid >> 6, lane = tid & 63;
  const int wm = wid >> 2, wn = wid & 3;

  // T1: XCD swizzle (nwg % 8 == 0), bn fastest within an XCD's chunk.
  int nwg = gridDim.x;
  int bid = blockIdx.x;
  int wg  = (bid & 7) * (nwg >> 3) + (bid >> 3);
  int bn = wg % Nb, bm = wg / Nb;
  const long rowBase = (long)bm * 256;
  const long colBase = (long)bn * 256;

  // Pre-swizzled global sources: linear LDS dest then holds swizzled data.
  const int colE = 8 * ((lane & 7) ^ (lane >> 3));
  const unsigned short* srcA[2][2];
  const unsigned short* srcB[2][2];
#pragma unroll
  for (int a = 0; a < 2; a++)
#pragma unroll
    for (int s = 0; s < 2; s++) {
      long rA = rowBase + a * 128 + s * 64 + wid * 8 + (lane >> 3);
      long rB = colBase + a * 128 + s * 64 + wid * 8 + (lane >> 3);
      srcA[a][s] = A  + rA * K + colE;
      srcB[a][s] = Bm + rB * K + colE;
    }

  f32x4 acc[8][4];
#pragma unroll
  for (int i = 0; i < 8; i++)
#pragma unroll
    for (int j = 0; j < 4; j++) acc[i][j] = (f32x4){0.f, 0.f, 0.f, 0.f};

  const int rowAl = wm * 64 + (lane & 15);
  const int rowBl = wn * 16 + (lane & 15);
  const int kb0   = (lane >> 4) * 16;
  const int sx    = (lane & 7) << 4;

  bf16x8 af[4][2], b0[2][2], b1[2][2];

  auto STAGE = [&](int p, int which, const unsigned short* s0, const unsigned short* s1) {
    char* d = &lds[p * 65536 + which * 16384 + wid * 1024];
    gload16(s0, d);
    gload16(s1, d + 8192);
  };
  auto LDA = [&](int p, int half) {
#pragma unroll
    for (int i = 0; i < 4; i++)
#pragma unroll
      for (int s = 0; s < 2; s++) {
        int off = p * 65536 + half * 16384 +
                  ((((i * 16 + rowAl) << 7) + s * 64 + kb0) ^ sx);
        af[i][s] = *(const bf16x8*)&lds[off];
      }
  };
  auto LDB = [&](bf16x8 bfr[2][2], int p, int bh) {
#pragma unroll
    for (int j = 0; j < 2; j++)
#pragma unroll
      for (int s = 0; s < 2; s++) {
        int off = p * 65536 + 32768 + bh * 16384 +
                  ((((j * 64 + rowBl) << 7) + s * 64 + kb0) ^ sx);
        bfr[j][s] = *(const bf16x8*)&lds[off];
      }
  };
  auto MM = [&](bf16x8 bfr[2][2], int ah, int bh) {
    __builtin_amdgcn_s_setprio(1);
#pragma unroll
    for (int i = 0; i < 4; i++)
#pragma unroll
      for (int j = 0; j < 2; j++)
#pragma unroll
        for (int s = 0; s < 2; s++)
          acc[ah * 4 + i][bh * 2 + j] = __builtin_amdgcn_mfma_f32_16x16x32_bf16(
              af[i][s], bfr[j][s], acc[ah * 4 + i][bh * 2 + j], 0, 0, 0);
    __builtin_amdgcn_s_setprio(0);
  };

#define BAR()   asm volatile("s_barrier" ::: "memory")
#define VM(n)   asm volatile("s_waitcnt vmcnt(" #n ")" ::: "memory")

  const int NT = K / 64;
  // Prologue: stage all of tile 0 (order A0,B0,B1,A1); A0,B0 must land now.
  STAGE(0, 0, srcA[0][0], srcA[0][1]);
  STAGE(0, 2, srcB[0][0], srcB[0][1]);
  STAGE(0, 3, srcB[1][0], srcB[1][1]);
  STAGE(0, 1, srcA[1][0], srcA[1][1]);
  VM(4);  // B1, A1 still in flight (drained by ph0/ph1 gates below)
  BAR();

#pragma unroll 2
  for (int t = 0; t < NT - 1; t++) {
    const int p = t & 1, q = p ^ 1;
    const int ko = (t + 1) * 64;
    // ph0: read A0,B0 | stage next A0' | MFMA (A0,B0) | gate B1 (needed ph1)
    LDA(p, 0); LDB(b0, p, 0);
    STAGE(q, 0, srcA[0][0] + ko, srcA[0][1] + ko);
    MM(b0, 0, 0);
    VM(4);
    BAR();
    // ph1: read B1 | stage next B0' | MFMA (A0,B1) | gate A1 (needed ph2)
    LDB(b1, p, 1);
    STAGE(q, 2, srcB[0][0] + ko, srcB[0][1] + ko);
    MM(b1, 0, 1);
    VM(4);
    BAR();
    // ph2: read A1 | stage next B1' | MFMA (A1,B1) | no gate
    LDA(p, 1);
    STAGE(q, 3, srcB[1][0] + ko, srcB[1][1] + ko);
    MM(b1, 1, 1);
    BAR();
    // ph3: b0 reused from regs | stage next A1' | MFMA (A1,B0) | gate A0',B0'
    STAGE(q, 1, srcA[1][0] + ko, srcA[1][1] + ko);
    MM(b0, 1, 0);
    VM(4);
    BAR();
  }
  // Final tile: no staging; drain B1 then A1 progressively.
  {
    const int p = (NT - 1) & 1;
    LDA(p, 0); LDB(b0, p, 0);
    MM(b0, 0, 0);
    VM(2);
    BAR();
    LDB(b1, p, 1);
    MM(b1, 0, 1);
    VM(0);
    BAR();
    LDA(p, 1);
    MM(b1, 1, 1);
    MM(b0, 1, 0);
  }
#undef BAR
#undef VM

  // Epilogue
  const int cc = lane & 15, r4 = (lane >> 4) * 4;
#pragma unroll
  for (int ig = 0; ig < 8; ig++) {
    long row = rowBase + (ig & 3) * 16 + wm * 64 + (ig >> 2) * 128 + r4;
#pragma unroll
    for (int j = 0; j < 4; j++) {
      long col = colBase + j * 64 + wn * 16 + cc;
      if (OUTBF) {
        unsigned short* Cb = (unsigned short*)Co;
#pragma unroll
        for (int r = 0; r < 4; r++)
          Cb[(row + r) * (long)Nd + col] = f2bf(acc[ig][j][r]);
      } else {
        float* Cf = (float*)Co;
        float d = Dv[col];
#pragma unroll
        for (int r = 0; r < 4; r++)
          Cf[(row + r) * (long)Nd + col] =
              acc[ig][j][r] + d * bf2f(ub[(row + r) * (long)Nd + col]);
      }
    }
  }
}

// ---------------- Chunked complex scan (Bu packed bf16 re|im) ----------------
__global__ void scan_carry(const unsigned* __restrict__ Bu,
                           const float* __restrict__ lam_re, const float* __restrict__ lam_im,
                           float2* __restrict__ V) {
  int idx  = blockIdx.x * 256 + threadIdx.x;
  int n    = idx & (NDIM - 1);
  int c    = (idx >> 9) & (NCHUNK - 1);
  int bloc = idx >> 15;
  float lr = lam_re[n], li = lam_im[n];
  float xr = 0.f, xi = 0.f;
  long base = ((long)bloc * TSEQ + c * LCHUNK) * NDIM + n;
#pragma unroll 4
  for (int j = 0; j < LCHUNK; j++) {
    unsigned pv = Bu[base + (long)j * NDIM];
    float br = bf2f((unsigned short)(pv & 0xffff));
    float bi = bf2f((unsigned short)(pv >> 16));
    float nr = lr * xr - li * xi + br;
    float ni = lr * xi + li * xr + bi;
    xr = nr; xi = ni;
  }
  V[idx] = make_float2(xr, xi);
}

__global__ void scan_combine(const float2* __restrict__ V,
                             const float* __restrict__ lamL_re, const float* __restrict__ lamL_im,
                             const float* __restrict__ x0r, const float* __restrict__ x0i,
                             int b0, float2* __restrict__ In) {
  int idx  = blockIdx.x * 256 + threadIdx.x;
  int n    = idx & (NDIM - 1);
  int bloc = idx >> 9;
  int b    = b0 + bloc;
  float lr = lamL_re[n], li = lamL_im[n];
  float sr = x0r[b * NDIM + n], si = x0i[b * NDIM + n];
  long base = (long)bloc * NCHUNK * NDIM + n;
  for (int c = 0; c < NCHUNK; c++) {
    In[base + c * NDIM] = make_float2(sr, si);
    float2 v = V[base + c * NDIM];
    float nr = lr * sr - li * si + v.x;
    float ni = lr * si + li * sr + v.y;
    sr = nr; si = ni;
  }
}

__global__ void scan_apply(const unsigned* __restrict__ Bu, const float2* __restrict__ In,
                           const float* __restrict__ lam_re, const float* __restrict__ lam_im,
                           unsigned int* __restrict__ xsb, float* __restrict__ fs,
                           int b0, int fs_mode) {
  int idx  = blockIdx.x * 256 + threadIdx.x;
  int n    = idx & (NDIM - 1);
  int c    = (idx >> 9) & (NCHUNK - 1);
  int bloc = idx >> 15;
  float lr = lam_re[n], li = lam_im[n];
  float2 s = In[idx];
  float xr = s.x, xi = s.y;
  long base = ((long)bloc * TSEQ + c * LCHUNK) * NDIM + n;
#pragma unroll 4
  for (int j = 0; j < LCHUNK; j++) {
    unsigned pv = Bu[base + (long)j * NDIM];
    float br = bf2f((unsigned short)(pv & 0xffff));
    float bi = bf2f((unsigned short)(pv >> 16));
    float nr = lr * xr - li * xi + br;
    float ni = lr * xi + li * xr + bi;
    xr = nr; xi = ni;
    xsb[base + (long)j * NDIM] = (unsigned)f2bf(xr) | ((unsigned)f2bf(xi) << 16);
  }
  if (c == NCHUNK - 1 && fs_mode >= 0) {
    int b = b0 + bloc;
    if (fs_mode == 1) {
      fs[(size_t)(b * NDIM + n) * 2]     = xr;
      fs[(size_t)(b * NDIM + n) * 2 + 1] = xi;
    } else {
      fs[(size_t)(b * NDIM + n)] = xr;
    }
  }
}

// ---------------- Host launch ----------------
extern "C" void kernel_launch(void* const* d_in, const int* in_sizes, int n_in,
                              void* d_out, int out_size, void* d_ws, size_t ws_size,
                              hipStream_t stream) {
  const float* x0r       = (const float*)d_in[0];
  const float* x0i       = (const float*)d_in[1];
  const float* u         = (const float*)d_in[2];
  const float* nu_log    = (const float*)d_in[3];
  const float* theta_log = (const float*)d_in[4];
  const float* B_re      = (const float*)d_in[5];
  const float* B_im      = (const float*)d_in[6];
  const float* C_re      = (const float*)d_in[7];
  const float* C_im      = (const float*)d_in[8];
  const float* Dv        = (const float*)d_in[9];

  char* ws = (char*)d_ws;
  size_t off = 0;
  auto alloc = [&](size_t bytes) {
    char* p = ws + off;
    off = (off + bytes + 255) & ~(size_t)255;
    return p;
  };

  float* lam_re  = (float*)alloc(NDIM * 4);
  float* lam_im  = (float*)alloc(NDIM * 4);
  float* gam     = (float*)alloc(NDIM * 4);
  float* lamL_re = (float*)alloc(NDIM * 4);
  float* lamL_im = (float*)alloc(NDIM * 4);
  unsigned short* Bcat = (unsigned short*)alloc((size_t)2 * NDIM * HDIM * 2);
  unsigned short* Ccat = (unsigned short*)alloc((size_t)HDIM * 2 * NDIM * 2);

  const size_t per_batch =
      (size_t)TSEQ * HDIM * 2 +       // u bf16
      (size_t)TSEQ * NDIM * 4 +       // Bu packed bf16 (re|im)
      (size_t)TSEQ * NDIM * 4 +       // xs packed bf16
      (size_t)2 * NCHUNK * NDIM * 8 + // V, In
      4096;
  int G = 16;
  while (G > 1 && off + (size_t)G * per_batch > ws_size) G >>= 1;

  ushort4*      ub  = (ushort4*)alloc((size_t)G * TSEQ * HDIM * 2);
  unsigned*     Bu  = (unsigned*)alloc((size_t)G * TSEQ * NDIM * 4);
  unsigned int* xsb = (unsigned int*)alloc((size_t)G * TSEQ * NDIM * 4);
  float2*       V   = (float2*)alloc((size_t)G * NCHUNK * NDIM * 8);
  float2*       In  = (float2*)alloc((size_t)G * NCHUNK * NDIM * 8);

  const long outs_elems = (long)BATCH * TSEQ * HDIM;
  long out0 = (long)out_size - outs_elems;
  int fs_mode;
  if (out0 >= 16384)     fs_mode = 1;
  else if (out0 >= 8192) fs_mode = 0;
  else { out0 = 0;       fs_mode = -1; }

  float* fs   = (float*)d_out;
  float* outs = (float*)d_out + out0;

  prep_params<<<1, NDIM, 0, stream>>>(nu_log, theta_log, lam_re, lam_im, gam, lamL_re, lamL_im);
  prep_bcat<<<(2 * NDIM * HDIM) / 256, 256, 0, stream>>>(B_re, B_im, gam, Bcat);
  prep_ccat<<<(HDIM * 2 * NDIM) / 256, 256, 0, stream>>>(C_re, C_im, Ccat);

  for (int b0 = 0; b0 < BATCH; b0 += G) {
    const float* ug = u + (size_t)b0 * TSEQ * HDIM;
    int Mloc = G * TSEQ;
    int n4 = Mloc * HDIM / 4;
    conv_u<<<(n4 + 255) / 256, 256, 0, stream>>>((const float4*)ug, ub, n4);

    // GEMM1: Bu[M, 2N] (bf16 packed) = ub[M,512] @ Bcat[1024,512]^T
    int nwg1 = (Mloc / 256) * 4;
    gemm8p<512, true><<<nwg1, 512, 0, stream>>>(
        (const unsigned short*)ub, Bcat, Bu, 4, 2 * NDIM, nullptr, nullptr);

    scan_carry<<<(G * NCHUNK * NDIM) / 256, 256, 0, stream>>>(Bu, lam_re, lam_im, V);
    scan_combine<<<(G * NDIM) / 256, 256, 0, stream>>>(
        V, lamL_re, lamL_im, x0r, x0i, b0, In);
    scan_apply<<<(G * NCHUNK * NDIM) / 256, 256, 0, stream>>>(
        Bu, In, lam_re, lam_im, xsb, fs, b0, fs_mode);

    // GEMM2: outs[M,512] = xsb[M,1024] @ Ccat[512,1024]^T + D*u
    int nwg2 = (Mloc / 256) * 2;
    gemm8p<1024, false><<<nwg2, 512, 0, stream>>>(
        (const unsigned short*)xsb, Ccat, outs + (size_t)b0 * TSEQ * HDIM,
        2, HDIM, (const unsigned short*)ub, Dv);
  }
}